// Round 6
// baseline (168.093 us; speedup 1.0000x reference)
//
#include <hip/hip_runtime.h>
#include <hip/hip_bf16.h>
#include <stdint.h>

// ---------------------------------------------------------------------------
// TrigramWriteMemoryAttention  (B=2, T=1024, D=1024, H=16, dh=64, pd=4)
// Fused buffer layout (bf16, row stride 4480):
//   cols 0:1024 Q | 1024:2048 K | 2048:3072 V | 3072:4096 mem_val | 4096:4480 small
// small cols (also written f32 to projf[2048][384]):
//   0:64 xw1a | 64:128 xw1b | 128:192 w2 | 192:256 r1 | 256:320 r2 | 320:336 gate
// ---------------------------------------------------------------------------

typedef __attribute__((ext_vector_type(8))) __bf16 bf16v8;
typedef __attribute__((ext_vector_type(8))) short  s16x8;
typedef __attribute__((ext_vector_type(4))) float  f32x4;

#define LOG2E 1.4426950408889634f

__device__ __forceinline__ float bf2f(short s) {
  union { uint32_t u; float f; } cv; cv.u = ((uint32_t)(uint16_t)s) << 16; return cv.f;
}
__device__ __forceinline__ short f2bf(float f) {
  union { float f; uint32_t u; } cv; cv.f = f;
  uint32_t r = cv.u + 0x7fffu + ((cv.u >> 16) & 1u);
  return (short)(r >> 16);
}

__device__ __forceinline__ f32x4 mfma_bf16(s16x8 a, s16x8 b, f32x4 c) {
  return __builtin_amdgcn_mfma_f32_16x16x32_bf16(
      __builtin_bit_cast(bf16v8, a), __builtin_bit_cast(bf16v8, b), c, 0, 0, 0);
}

__device__ __forceinline__ void gload_lds16(const void* g, void* l) {
  __builtin_amdgcn_global_load_lds(
      (const __attribute__((address_space(1))) uint32_t*)g,
      (__attribute__((address_space(3))) uint32_t*)l, 16, 0, 0);
}

// ---------------- conversions ----------------

__global__ void k_cvt(const float* __restrict__ in, short* __restrict__ out, int n) {
  int i = (blockIdx.x * 256 + threadIdx.x) * 4;
  if (i < n) {
    float4 v = *(const float4*)&in[i];
    short4 o;
    o.x = f2bf(v.x); o.y = f2bf(v.y); o.z = f2bf(v.z); o.w = f2bf(v.w);
    *(short4*)&out[i] = o;
  }
}

// W[K][N] f32 -> Wt[N][K] bf16   (K,N multiples of 32)
__global__ void k_tconv(const float* __restrict__ W, short* __restrict__ Wt, int K, int N) {
  __shared__ float tile[32][33];
  const int n0 = blockIdx.x * 32, k0 = blockIdx.y * 32;
  const int tx = threadIdx.x, ty = threadIdx.y;  // blockDim 32x8
#pragma unroll
  for (int i = 0; i < 4; i++)
    tile[ty + i * 8][tx] = W[(size_t)(k0 + ty + i * 8) * N + n0 + tx];
  __syncthreads();
#pragma unroll
  for (int i = 0; i < 4; i++)
    Wt[(size_t)(n0 + ty + i * 8) * K + k0 + tx] = f2bf(tile[tx][ty + i * 8]);
}

// Build smallwT rows of btall[4096:4480][1024] bf16, plus biasAll[4480] f32.
__global__ void k_smallw(const float* __restrict__ w1w, const float* __restrict__ w2w,
                         const float* __restrict__ r1w, const float* __restrict__ r2w,
                         const float* __restrict__ gw, const float* __restrict__ qkvb,
                         const float* __restrict__ mvb, short* __restrict__ out,
                         float* __restrict__ biasAll) {
  if (blockIdx.x >= 1536) {  // bias region
    const int i = (blockIdx.x - 1536) * 256 + threadIdx.x;
    if (i < 4480) {
      float v = 0.f;
      if (i < 3072) v = qkvb[i];
      else if (i < 4096) v = mvb[i - 3072];
      biasAll[i] = v;
    }
    return;
  }
  const int idx = blockIdx.x * 256 + threadIdx.x;  // 384*1024
  const int r = idx >> 10, k = idx & 1023;
  float v = 0.f;
  if (r < 64)       v = w1w[(size_t)k * 64 + r];
  else if (r < 128) v = w1w[(size_t)(1024 + k) * 64 + (r - 64)];
  else if (r < 192) v = w2w[(size_t)k * 64 + (r - 128)];
  else if (r < 256) v = r1w[(size_t)k * 64 + (r - 192)];
  else if (r < 320) v = r2w[(size_t)k * 64 + (r - 256)];
  else if (r < 336) v = gw[(size_t)k * 16 + (r - 320)];
  out[idx] = f2bf(v);
}

// ---------------- fused projection GEMM ----------------
// C[2048][4480] = xb @ btall^T + biasAll; proj cols (>=4096) go to projf f32.

__global__ __launch_bounds__(256) void k_gemmF(const short* __restrict__ A,
                                               const short* __restrict__ Bt,
                                               short* __restrict__ C,
                                               const float* __restrict__ bias,
                                               float* __restrict__ projf) {
  const int N = 4480, K = 1024;
  __shared__ short As[128 * 32];
  __shared__ short Bs[128 * 32];
  const int m0 = blockIdx.x * 128, n0 = blockIdx.y * 128;
  const int tid = threadIdx.x;
  const int lane = tid & 63, w = tid >> 6;
  const int wr = (w >> 1) * 64, wc = (w & 1) * 64;
  const int l15 = lane & 15, lg = lane >> 4;
  f32x4 acc[4][4] = {};
  for (int k0 = 0; k0 < K; k0 += 32) {
#pragma unroll
    for (int p = 0; p < 2; p++) {
      const int e = p * 256 + tid;
      const int r = e >> 2, c8 = (e & 3) << 3;
      gload_lds16(A + (size_t)(m0 + r) * K + k0 + c8, As + e * 8);
      gload_lds16(Bt + (size_t)(n0 + r) * K + k0 + c8, Bs + e * 8);
    }
    __syncthreads();
    s16x8 af[4], bfv[4];
#pragma unroll
    for (int i = 0; i < 4; i++) {
      af[i]  = *(const s16x8*)&As[(wr + i * 16 + l15) * 32 + lg * 8];
      bfv[i] = *(const s16x8*)&Bs[(wc + i * 16 + l15) * 32 + lg * 8];
    }
#pragma unroll
    for (int mi = 0; mi < 4; mi++)
#pragma unroll
      for (int ni = 0; ni < 4; ni++)
        acc[mi][ni] = mfma_bf16(af[mi], bfv[ni], acc[mi][ni]);
    __syncthreads();
  }
  const bool isproj = (n0 >= 4096);
#pragma unroll
  for (int mi = 0; mi < 4; mi++)
#pragma unroll
    for (int ni = 0; ni < 4; ni++) {
      const int col = n0 + wc + ni * 16 + l15;
      const float bv = bias[col];
#pragma unroll
      for (int r = 0; r < 4; r++) {
        const int row = m0 + wr + mi * 16 + lg * 4 + r;
        const float v = acc[mi][ni][r] + bv;
        if (isproj) projf[(size_t)row * 384 + (col - 4096)] = v;
        else        C[(size_t)row * 4480 + col] = f2bf(v);
      }
    }
}

// ---------------- generic GEMM (out-projection) ----------------

__global__ __launch_bounds__(256) void k_gemm(const short* __restrict__ A,
                                              const short* __restrict__ Bt,
                                              float* __restrict__ C,
                                              const float* __restrict__ bias,
                                              int N, int K) {
  __shared__ short As[128 * 32];
  __shared__ short Bs[128 * 32];
  const int m0 = blockIdx.x * 128, n0 = blockIdx.y * 128;
  const int tid = threadIdx.x;
  const int lane = tid & 63, w = tid >> 6;
  const int wr = (w >> 1) * 64, wc = (w & 1) * 64;
  const int l15 = lane & 15, lg = lane >> 4;
  f32x4 acc[4][4] = {};
  for (int k0 = 0; k0 < K; k0 += 32) {
#pragma unroll
    for (int p = 0; p < 2; p++) {
      const int e = p * 256 + tid;
      const int r = e >> 2, c8 = (e & 3) << 3;
      gload_lds16(A + (size_t)(m0 + r) * K + k0 + c8, As + e * 8);
      gload_lds16(Bt + (size_t)(n0 + r) * K + k0 + c8, Bs + e * 8);
    }
    __syncthreads();
    s16x8 af[4], bfv[4];
#pragma unroll
    for (int i = 0; i < 4; i++) {
      af[i]  = *(const s16x8*)&As[(wr + i * 16 + l15) * 32 + lg * 8];
      bfv[i] = *(const s16x8*)&Bs[(wc + i * 16 + l15) * 32 + lg * 8];
    }
#pragma unroll
    for (int mi = 0; mi < 4; mi++)
#pragma unroll
      for (int ni = 0; ni < 4; ni++)
        acc[mi][ni] = mfma_bf16(af[mi], bfv[ni], acc[mi][ni]);
    __syncthreads();
  }
#pragma unroll
  for (int mi = 0; mi < 4; mi++)
#pragma unroll
    for (int ni = 0; ni < 4; ni++) {
      const int col = n0 + wc + ni * 16 + l15;
      const float bv = bias ? bias[col] : 0.f;
#pragma unroll
      for (int r = 0; r < 4; r++) {
        const int row = m0 + wr + mi * 16 + lg * 4 + r;
        C[(size_t)row * N + col] = acc[mi][ni][r] + bv;
      }
    }
}

// ---------------- V transpose: fused V cols -> vtg[bh][64][1024] ----------------

__global__ void k_vtr(const short* __restrict__ fused, short* __restrict__ vtg) {
  __shared__ short tile[32][33];
  const int bh = blockIdx.z;
  const int b = bh >> 4, h = bh & 15;
  const int t0 = blockIdx.x * 32, d0 = blockIdx.y * 32;
  const int tx = threadIdx.x, ty = threadIdx.y;  // 32x8
#pragma unroll
  for (int i = 0; i < 4; i++)
    tile[ty + i * 8][tx] =
        fused[(size_t)(b * 1024 + t0 + ty + i * 8) * 4480 + 2048 + h * 64 + d0 + tx];
  __syncthreads();
#pragma unroll
  for (int i = 0; i < 4; i++)
    vtg[(size_t)(bh * 64 + d0 + ty + i * 8) * 1024 + t0 + tx] = tile[tx][ty + i * 8];
}

// ---------------- flash attention ----------------
// 1024 single-wave blocks: xcd = id&7, bh = xcd + 8*((id>>3)&3), qt = id>>5.
// One wave owns a 32-row q-tile; NO barriers, NO K/V LDS: K and V^T MFMA
// fragments are read directly from global (L2-resident via the XCD pinning;
// 4 lanes x 16B cover each 128B row -> line-coalesced).  LDS only holds the
// wave-private P exchange.  All 1024 blocks co-resident (4/CU), independent.

__global__ __launch_bounds__(64) void k_attn(const short* __restrict__ fused,
                                             const short* __restrict__ vtg,
                                             short* __restrict__ outp) {
  const int id = blockIdx.x;
  const int bh = (id & 7) + 8 * ((id >> 3) & 3);
  const int qt = id >> 5;              // 0..31
  const int b = bh >> 4, h = bh & 15;
  const int lane = threadIdx.x;
  const int l15 = lane & 15, lg = lane >> 4;
  const int q0 = qt * 32;
  const int nkv = (qt >> 1) + 1;
  __shared__ short Pl[32 * 72];
  const short* base = fused + (size_t)b * 1024 * 4480;
  const short* kbase = base + 1024 + h * 64;
  const short* vbase = vtg + (size_t)bh * 64 * 1024;
  short* op = outp + (size_t)b * 1024 * 1024;

  s16x8 qf[2][2];
#pragma unroll
  for (int qq = 0; qq < 2; qq++)
#pragma unroll
    for (int ks = 0; ks < 2; ks++)
      qf[qq][ks] = *(const s16x8*)&base[(size_t)(q0 + qq * 16 + l15) * 4480 +
                                        h * 64 + ks * 32 + lg * 8];

  f32x4 O[2][4] = {};
  float m_run[2][4], l_run[2][4];
#pragma unroll
  for (int qq = 0; qq < 2; qq++)
#pragma unroll
    for (int r = 0; r < 4; r++) { m_run[qq][r] = -1e30f; l_run[qq][r] = 0.f; }

  for (int kt = 0; kt < nkv; kt++) {
    const int kv0 = kt * 64;

    // K fragments direct from global (L2)
    s16x8 kf0[4], kf1[4];
#pragma unroll
    for (int sf = 0; sf < 4; sf++) {
      const short* kr = kbase + (size_t)(kv0 + sf * 16 + l15) * 4480;
      kf0[sf] = *(const s16x8*)&kr[lg * 8];
      kf1[sf] = *(const s16x8*)&kr[32 + lg * 8];
    }
    // V^T fragments direct from global (issued early, consumed after softmax)
    s16x8 vf[2][4];
#pragma unroll
    for (int ks = 0; ks < 2; ks++)
#pragma unroll
      for (int nf = 0; nf < 4; nf++)
        vf[ks][nf] = *(const s16x8*)&vbase[(size_t)(nf * 16 + l15) * 1024 +
                                           kv0 + ks * 32 + lg * 8];

    // S = Q @ K^T
    f32x4 S[2][4] = {};
    __builtin_amdgcn_s_setprio(1);
#pragma unroll
    for (int sf = 0; sf < 4; sf++)
#pragma unroll
      for (int qq = 0; qq < 2; qq++) {
        S[qq][sf] = mfma_bf16(qf[qq][0], kf0[sf], S[qq][sf]);
        S[qq][sf] = mfma_bf16(qf[qq][1], kf1[sf], S[qq][sf]);
      }
    __builtin_amdgcn_s_setprio(0);

    const bool diag = (kt == nkv - 1);
#pragma unroll
    for (int qq = 0; qq < 2; qq++) {
#pragma unroll
      for (int sf = 0; sf < 4; sf++)
#pragma unroll
        for (int r = 0; r < 4; r++) {
          float v = S[qq][sf][r] * 0.125f;
          if (diag) {
            const int sg = kv0 + sf * 16 + l15;
            const int qg = q0 + qq * 16 + lg * 4 + r;
            if (sg > qg) v = -1e30f;
          }
          S[qq][sf][r] = v;
        }
#pragma unroll
      for (int r = 0; r < 4; r++) {
        float pm = fmaxf(fmaxf(S[qq][0][r], S[qq][1][r]),
                         fmaxf(S[qq][2][r], S[qq][3][r]));
        pm = fmaxf(pm, __shfl_xor(pm, 1, 64));
        pm = fmaxf(pm, __shfl_xor(pm, 2, 64));
        pm = fmaxf(pm, __shfl_xor(pm, 4, 64));
        pm = fmaxf(pm, __shfl_xor(pm, 8, 64));
        const float mn = fmaxf(m_run[qq][r], pm);
        const float fac = exp2f((m_run[qq][r] - mn) * LOG2E);
        m_run[qq][r] = mn;
        float rs = 0.f;
#pragma unroll
        for (int sf = 0; sf < 4; sf++) {
          float p = (S[qq][sf][r] <= -1e29f) ? 0.f : exp2f((S[qq][sf][r] - mn) * LOG2E);
          rs += p;
          Pl[(qq * 16 + lg * 4 + r) * 72 + sf * 16 + l15] = f2bf(p);
        }
        rs += __shfl_xor(rs, 1, 64);
        rs += __shfl_xor(rs, 2, 64);
        rs += __shfl_xor(rs, 4, 64);
        rs += __shfl_xor(rs, 8, 64);
        l_run[qq][r] = l_run[qq][r] * fac + rs;
#pragma unroll
        for (int nf = 0; nf < 4; nf++) O[qq][nf][r] *= fac;
      }
    }

    // O += P @ V   (wave-private LDS exchange; compiler inserts lgkm waits)
    __builtin_amdgcn_s_setprio(1);
#pragma unroll
    for (int qq = 0; qq < 2; qq++)
#pragma unroll
      for (int ks = 0; ks < 2; ks++) {
        s16x8 pfr = *(const s16x8*)&Pl[(qq * 16 + l15) * 72 + ks * 32 + lg * 8];
#pragma unroll
        for (int nf = 0; nf < 4; nf++)
          O[qq][nf] = mfma_bf16(pfr, vf[ks][nf], O[qq][nf]);
      }
    __builtin_amdgcn_s_setprio(0);
  }

#pragma unroll
  for (int qq = 0; qq < 2; qq++)
#pragma unroll
    for (int nf = 0; nf < 4; nf++)
#pragma unroll
      for (int r = 0; r < 4; r++) {
        const int row = q0 + qq * 16 + lg * 4 + r;
        op[(size_t)row * 1024 + h * 64 + nf * 16 + l15] =
            f2bf(O[qq][nf][r] / l_run[qq][r]);
      }
}

// ---------------- Plucker lines ----------------

__device__ __forceinline__ void exterior6(const float p1[4], const float p2[4], float L[6]) {
  L[0] = p1[0] * p2[1] - p1[1] * p2[0];
  L[1] = p1[0] * p2[2] - p1[2] * p2[0];
  L[2] = p1[0] * p2[3] - p1[3] * p2[0];
  L[3] = p1[1] * p2[2] - p1[2] * p2[1];
  L[4] = p1[1] * p2[3] - p1[3] * p2[1];
  L[5] = p1[2] * p2[3] - p1[3] * p2[2];
  float n = sqrtf(L[0] * L[0] + L[1] * L[1] + L[2] * L[2] +
                  L[3] * L[3] + L[4] * L[4] + L[5] * L[5]);
  float inv = 1.f / fmaxf(n, 1e-12f);
#pragma unroll
  for (int j = 0; j < 6; j++) L[j] *= inv;
}

// jw layout: SoA [bh][6][1024]; rl layout: AoS [bh][t][6]
__global__ void k_lines(const float* __restrict__ proj, const float* __restrict__ Jm,
                        float* __restrict__ jw, float* __restrict__ rl) {
  const int idx = blockIdx.x * 256 + threadIdx.x;  // 32768
  const int t = idx & 1023, h = (idx >> 10) & 15, b = idx >> 14;
  const int n = b * 1024 + t;
  const int bh = b * 16 + h;
  float p1[4], p2[4], L[6];
#pragma unroll
  for (int p = 0; p < 4; p++) {
    float a  = (t >= 2) ? proj[(size_t)(n - 2) * 384 + h * 4 + p] : 0.f;
    float bb = (t >= 1) ? proj[(size_t)(n - 1) * 384 + 64 + h * 4 + p] : 0.f;
    p1[p] = a + bb;
    p2[p] = proj[(size_t)n * 384 + 128 + h * 4 + p];
  }
  exterior6(p1, p2, L);
  const size_t jo = (size_t)bh * 6144 + t;
#pragma unroll
  for (int j = 0; j < 6; j++) {
    float s = 0.f;
#pragma unroll
    for (int i = 0; i < 6; i++) s += L[i] * Jm[i * 6 + j];
    jw[jo + (size_t)j * 1024] = s;
  }
#pragma unroll
  for (int p = 0; p < 4; p++) {
    p1[p] = proj[(size_t)n * 384 + 192 + h * 4 + p];
    p2[p] = proj[(size_t)n * 384 + 256 + h * 4 + p];
  }
  exterior6(p1, p2, L);
  const size_t ro = ((size_t)bh * 1024 + t) * 6;
#pragma unroll
  for (int j = 0; j < 6; j++) rl[ro + j] = L[j];
}

// ---------------- decayed memory score ----------------

__global__ __launch_bounds__(256) void k_mscore(const float* __restrict__ jw,
                                                const float* __restrict__ rl,
                                                const float* __restrict__ dlog,
                                                float* __restrict__ ms) {
  const int gtid = blockIdx.x * 256 + threadIdx.x;
  const int wid = gtid >> 6, lane = gtid & 63;
  const int bh = wid >> 10, t = wid & 1023;
  const int h = bh & 15, b = bh >> 4;
  const float d = 1.f / (1.f + expf(-dlog[h]));
  const float l2d = log2f(d);
  const float* jwp = jw + (size_t)bh * 6144;
  const float* rp = rl + ((size_t)bh * 1024 + t) * 6;
  const float r0 = rp[0], r1 = rp[1], r2 = rp[2], r3 = rp[3], r4 = rp[4], r5 = rp[5];
  float wgt = exp2f((float)(t - lane) * l2d);
  const float gw = exp2f(-64.f * l2d);
  float acc = 0.f;
  for (int s = lane; s < t; s += 64) {
    const float dot = r0 * jwp[s] + r1 * jwp[1024 + s] + r2 * jwp[2048 + s] +
                      r3 * jwp[3072 + s] + r4 * jwp[4096 + s] + r5 * jwp[5120 + s];
    acc += wgt * dot * dot;
    wgt *= gw;
  }
  acc += __shfl_xor(acc, 1, 64);
  acc += __shfl_xor(acc, 2, 64);
  acc += __shfl_xor(acc, 4, 64);
  acc += __shfl_xor(acc, 8, 64);
  acc += __shfl_xor(acc, 16, 64);
  acc += __shfl_xor(acc, 32, 64);
  if (lane == 0) ms[((size_t)(b * 1024 + t)) * 16 + h] = acc;
}

// ---------------- combine: comb = bf16(attn + gated*mem_val) ----------------

__global__ __launch_bounds__(256) void k_combine(const short* __restrict__ attn,
                                                 const short* __restrict__ fused,
                                                 const float* __restrict__ proj,
                                                 const float* __restrict__ ms,
                                                 const float* __restrict__ mem_scale,
                                                 const float* __restrict__ gate_b,
                                                 short* __restrict__ comb) {
  const int n = blockIdx.x;
  const int tid = threadIdx.x;
  __shared__ float gsh;
  if (tid < 16) {
    const float gp = proj[(size_t)n * 384 + 320 + tid] + gate_b[tid];
    const float g = 1.f / (1.f + expf(-gp));
    const float sc = ms[(size_t)n * 16 + tid] * mem_scale[tid];
    const float sg = 1.f / (1.f + expf(-sc));
    float v = sg * g;
    v += __shfl_xor(v, 1, 64);
    v += __shfl_xor(v, 2, 64);
    v += __shfl_xor(v, 4, 64);
    v += __shfl_xor(v, 8, 64);
    if (tid == 0) gsh = v * (1.f / 16.f);
  }
  __syncthreads();
  const float g = gsh;
  const int c0 = tid * 4;
  short4 av = *(const short4*)&attn[(size_t)n * 1024 + c0];
  short4 mvv = *(const short4*)&fused[(size_t)n * 4480 + 3072 + c0];
  short4 ov;
  ov.x = f2bf(bf2f(av.x) + g * bf2f(mvv.x));
  ov.y = f2bf(bf2f(av.y) + g * bf2f(mvv.y));
  ov.z = f2bf(bf2f(av.z) + g * bf2f(mvv.z));
  ov.w = f2bf(bf2f(av.w) + g * bf2f(mvv.w));
  *(short4*)&comb[(size_t)n * 1024 + c0] = ov;
}

// ---------------------------------------------------------------------------

extern "C" void kernel_launch(void* const* d_in, const int* in_sizes, int n_in,
                              void* d_out, int out_size, void* d_ws, size_t ws_size,
                              hipStream_t stream) {
  const float* x    = (const float*)d_in[0];
  const float* qkvw = (const float*)d_in[1];
  const float* qkvb = (const float*)d_in[2];
  const float* w1w  = (const float*)d_in[3];
  const float* w2w  = (const float*)d_in[4];
  const float* r1w  = (const float*)d_in[5];
  const float* r2w  = (const float*)d_in[6];
  const float* mvw  = (const float*)d_in[7];
  const float* mvb  = (const float*)d_in[8];
  const float* gw   = (const float*)d_in[9];
  const float* gb   = (const float*)d_in[10];
  const float* msc  = (const float*)d_in[11];
  const float* ow   = (const float*)d_in[12];
  const float* ob   = (const float*)d_in[13];
  const float* dlog = (const float*)d_in[14];
  const float* Jm   = (const float*)d_in[15];
  float* out = (float*)d_out;

  char* wsp = (char*)d_ws;
  auto alloc = [&](size_t bytes) {
    char* p = wsp;
    wsp += (bytes + 255) & ~(size_t)255;
    return p;
  };
  short* xb     = (short*)alloc((size_t)2048 * 1024 * 2);
  short* btall  = (short*)alloc((size_t)4480 * 1024 * 2);
  short* owT    = (short*)alloc((size_t)1024 * 1024 * 2);
  short* fusedC = (short*)alloc((size_t)2048 * 4480 * 2);
  float* projf  = (float*)alloc((size_t)2048 * 384 * 4);
  float* biasA  = (float*)alloc((size_t)4480 * 4);
  short* vtg    = (short*)alloc((size_t)32 * 64 * 1024 * 2);
  short* attnO  = (short*)alloc((size_t)2048 * 1024 * 2);
  short* comb   = (short*)alloc((size_t)2048 * 1024 * 2);
  float* jwb    = (float*)alloc((size_t)32 * 6144 * 4);
  float* rlb    = (float*)alloc((size_t)32768 * 6 * 4);
  float* msb    = (float*)alloc((size_t)2048 * 16 * 4);

  k_cvt<<<2048, 256, 0, stream>>>(x, xb, 2048 * 1024);
  dim3 tb(32, 8);
  k_tconv<<<dim3(96, 32), tb, 0, stream>>>(qkvw, btall, 1024, 3072);
  k_tconv<<<dim3(32, 32), tb, 0, stream>>>(mvw, btall + (size_t)3072 * 1024, 1024, 1024);
  k_tconv<<<dim3(32, 32), tb, 0, stream>>>(ow, owT, 1024, 1024);
  k_smallw<<<1554, 256, 0, stream>>>(w1w, w2w, r1w, r2w, gw, qkvb, mvb,
                                     btall + (size_t)4096 * 1024, biasA);

  k_gemmF<<<dim3(16, 35), 256, 0, stream>>>(xb, btall, fusedC, biasA, projf);

  k_vtr<<<dim3(32, 2, 32), tb, 0, stream>>>(fusedC, vtg);
  k_attn<<<1024, 64, 0, stream>>>(fusedC, vtg, attnO);

  k_lines<<<128, 256, 0, stream>>>(projf, Jm, jwb, rlb);
  k_mscore<<<8192, 256, 0, stream>>>(jwb, rlb, dlog, msb);
  k_combine<<<2048, 256, 0, stream>>>(attnO, fusedC, projf, msb, msc, gb, comb);

  k_gemm<<<dim3(16, 8), 256, 0, stream>>>(comb, owT, out, ob, 1024, 1024);
}

// Round 7
// 143.714 us; speedup vs baseline: 1.1696x; 1.1696x over previous
//
#include <hip/hip_runtime.h>
#include <hip/hip_bf16.h>
#include <stdint.h>

// ---------------------------------------------------------------------------
// TrigramWriteMemoryAttention  (B=2, T=1024, D=1024, H=16, dh=64, pd=4)
// Fused buffer layout (bf16, row stride 4480):
//   cols 0:1024 Q | 1024:2048 K | 2048:3072 V | 3072:4096 mem_val | 4096:4480 small
// small cols (also written f32 to projf[2048][384]):
//   0:64 xw1a | 64:128 xw1b | 128:192 w2 | 192:256 r1 | 256:320 r2 | 320:336 gate
// ---------------------------------------------------------------------------

typedef __attribute__((ext_vector_type(8))) __bf16 bf16v8;
typedef __attribute__((ext_vector_type(8))) short  s16x8;
typedef __attribute__((ext_vector_type(4))) float  f32x4;

#define LOG2E 1.4426950408889634f

__device__ __forceinline__ float bf2f(short s) {
  union { uint32_t u; float f; } cv; cv.u = ((uint32_t)(uint16_t)s) << 16; return cv.f;
}
__device__ __forceinline__ short f2bf(float f) {
  union { float f; uint32_t u; } cv; cv.f = f;
  uint32_t r = cv.u + 0x7fffu + ((cv.u >> 16) & 1u);
  return (short)(r >> 16);
}

__device__ __forceinline__ f32x4 mfma_bf16(s16x8 a, s16x8 b, f32x4 c) {
  return __builtin_amdgcn_mfma_f32_16x16x32_bf16(
      __builtin_bit_cast(bf16v8, a), __builtin_bit_cast(bf16v8, b), c, 0, 0, 0);
}

__device__ __forceinline__ void gload_lds16(const void* g, void* l) {
  __builtin_amdgcn_global_load_lds(
      (const __attribute__((address_space(1))) uint32_t*)g,
      (__attribute__((address_space(3))) uint32_t*)l, 16, 0, 0);
}

// ---------------- conversions ----------------

__global__ void k_cvt(const float* __restrict__ in, short* __restrict__ out, int n) {
  int i = (blockIdx.x * 256 + threadIdx.x) * 4;
  if (i < n) {
    float4 v = *(const float4*)&in[i];
    short4 o;
    o.x = f2bf(v.x); o.y = f2bf(v.y); o.z = f2bf(v.z); o.w = f2bf(v.w);
    *(short4*)&out[i] = o;
  }
}

// W[K][N] f32 -> Wt[N][K] bf16   (K,N multiples of 32)
__global__ void k_tconv(const float* __restrict__ W, short* __restrict__ Wt, int K, int N) {
  __shared__ float tile[32][33];
  const int n0 = blockIdx.x * 32, k0 = blockIdx.y * 32;
  const int tx = threadIdx.x, ty = threadIdx.y;  // blockDim 32x8
#pragma unroll
  for (int i = 0; i < 4; i++)
    tile[ty + i * 8][tx] = W[(size_t)(k0 + ty + i * 8) * N + n0 + tx];
  __syncthreads();
#pragma unroll
  for (int i = 0; i < 4; i++)
    Wt[(size_t)(n0 + ty + i * 8) * K + k0 + tx] = f2bf(tile[tx][ty + i * 8]);
}

// Build smallwT rows of btall[4096:4480][1024] bf16, plus biasAll[4480] f32.
__global__ void k_smallw(const float* __restrict__ w1w, const float* __restrict__ w2w,
                         const float* __restrict__ r1w, const float* __restrict__ r2w,
                         const float* __restrict__ gw, const float* __restrict__ qkvb,
                         const float* __restrict__ mvb, short* __restrict__ out,
                         float* __restrict__ biasAll) {
  if (blockIdx.x >= 1536) {  // bias region
    const int i = (blockIdx.x - 1536) * 256 + threadIdx.x;
    if (i < 4480) {
      float v = 0.f;
      if (i < 3072) v = qkvb[i];
      else if (i < 4096) v = mvb[i - 3072];
      biasAll[i] = v;
    }
    return;
  }
  const int idx = blockIdx.x * 256 + threadIdx.x;  // 384*1024
  const int r = idx >> 10, k = idx & 1023;
  float v = 0.f;
  if (r < 64)       v = w1w[(size_t)k * 64 + r];
  else if (r < 128) v = w1w[(size_t)(1024 + k) * 64 + (r - 64)];
  else if (r < 192) v = w2w[(size_t)k * 64 + (r - 128)];
  else if (r < 256) v = r1w[(size_t)k * 64 + (r - 192)];
  else if (r < 320) v = r2w[(size_t)k * 64 + (r - 256)];
  else if (r < 336) v = gw[(size_t)k * 16 + (r - 320)];
  out[idx] = f2bf(v);
}

// ---------------- fused projection GEMM ----------------
// C[2048][4480] = xb @ btall^T + biasAll; proj cols (>=4096) go to projf f32.

__global__ __launch_bounds__(256) void k_gemmF(const short* __restrict__ A,
                                               const short* __restrict__ Bt,
                                               short* __restrict__ C,
                                               const float* __restrict__ bias,
                                               float* __restrict__ projf) {
  const int N = 4480, K = 1024;
  __shared__ short As[128 * 32];
  __shared__ short Bs[128 * 32];
  const int m0 = blockIdx.x * 128, n0 = blockIdx.y * 128;
  const int tid = threadIdx.x;
  const int lane = tid & 63, w = tid >> 6;
  const int wr = (w >> 1) * 64, wc = (w & 1) * 64;
  const int l15 = lane & 15, lg = lane >> 4;
  f32x4 acc[4][4] = {};
  for (int k0 = 0; k0 < K; k0 += 32) {
#pragma unroll
    for (int p = 0; p < 2; p++) {
      const int e = p * 256 + tid;
      const int r = e >> 2, c8 = (e & 3) << 3;
      gload_lds16(A + (size_t)(m0 + r) * K + k0 + c8, As + e * 8);
      gload_lds16(Bt + (size_t)(n0 + r) * K + k0 + c8, Bs + e * 8);
    }
    __syncthreads();
    s16x8 af[4], bfv[4];
#pragma unroll
    for (int i = 0; i < 4; i++) {
      af[i]  = *(const s16x8*)&As[(wr + i * 16 + l15) * 32 + lg * 8];
      bfv[i] = *(const s16x8*)&Bs[(wc + i * 16 + l15) * 32 + lg * 8];
    }
#pragma unroll
    for (int mi = 0; mi < 4; mi++)
#pragma unroll
      for (int ni = 0; ni < 4; ni++)
        acc[mi][ni] = mfma_bf16(af[mi], bfv[ni], acc[mi][ni]);
    __syncthreads();
  }
  const bool isproj = (n0 >= 4096);
#pragma unroll
  for (int mi = 0; mi < 4; mi++)
#pragma unroll
    for (int ni = 0; ni < 4; ni++) {
      const int col = n0 + wc + ni * 16 + l15;
      const float bv = bias[col];
#pragma unroll
      for (int r = 0; r < 4; r++) {
        const int row = m0 + wr + mi * 16 + lg * 4 + r;
        const float v = acc[mi][ni][r] + bv;
        if (isproj) projf[(size_t)row * 384 + (col - 4096)] = v;
        else        C[(size_t)row * 4480 + col] = f2bf(v);
      }
    }
}

// ---------------- generic GEMM (out-projection) ----------------

__global__ __launch_bounds__(256) void k_gemm(const short* __restrict__ A,
                                              const short* __restrict__ Bt,
                                              float* __restrict__ C,
                                              const float* __restrict__ bias,
                                              int N, int K) {
  __shared__ short As[128 * 32];
  __shared__ short Bs[128 * 32];
  const int m0 = blockIdx.x * 128, n0 = blockIdx.y * 128;
  const int tid = threadIdx.x;
  const int lane = tid & 63, w = tid >> 6;
  const int wr = (w >> 1) * 64, wc = (w & 1) * 64;
  const int l15 = lane & 15, lg = lane >> 4;
  f32x4 acc[4][4] = {};
  for (int k0 = 0; k0 < K; k0 += 32) {
#pragma unroll
    for (int p = 0; p < 2; p++) {
      const int e = p * 256 + tid;
      const int r = e >> 2, c8 = (e & 3) << 3;
      gload_lds16(A + (size_t)(m0 + r) * K + k0 + c8, As + e * 8);
      gload_lds16(Bt + (size_t)(n0 + r) * K + k0 + c8, Bs + e * 8);
    }
    __syncthreads();
    s16x8 af[4], bfv[4];
#pragma unroll
    for (int i = 0; i < 4; i++) {
      af[i]  = *(const s16x8*)&As[(wr + i * 16 + l15) * 32 + lg * 8];
      bfv[i] = *(const s16x8*)&Bs[(wc + i * 16 + l15) * 32 + lg * 8];
    }
#pragma unroll
    for (int mi = 0; mi < 4; mi++)
#pragma unroll
      for (int ni = 0; ni < 4; ni++)
        acc[mi][ni] = mfma_bf16(af[mi], bfv[ni], acc[mi][ni]);
    __syncthreads();
  }
#pragma unroll
  for (int mi = 0; mi < 4; mi++)
#pragma unroll
    for (int ni = 0; ni < 4; ni++) {
      const int col = n0 + wc + ni * 16 + l15;
      const float bv = bias ? bias[col] : 0.f;
#pragma unroll
      for (int r = 0; r < 4; r++) {
        const int row = m0 + wr + mi * 16 + lg * 4 + r;
        C[(size_t)row * N + col] = acc[mi][ni][r] + bv;
      }
    }
}

// ---------------- V transpose: fused V cols -> vtg[bh][64][1024] ----------------

__global__ void k_vtr(const short* __restrict__ fused, short* __restrict__ vtg) {
  __shared__ short tile[32][33];
  const int bh = blockIdx.z;
  const int b = bh >> 4, h = bh & 15;
  const int t0 = blockIdx.x * 32, d0 = blockIdx.y * 32;
  const int tx = threadIdx.x, ty = threadIdx.y;  // 32x8
#pragma unroll
  for (int i = 0; i < 4; i++)
    tile[ty + i * 8][tx] =
        fused[(size_t)(b * 1024 + t0 + ty + i * 8) * 4480 + 2048 + h * 64 + d0 + tx];
  __syncthreads();
#pragma unroll
  for (int i = 0; i < 4; i++)
    vtg[(size_t)(bh * 64 + d0 + ty + i * 8) * 1024 + t0 + tx] = tile[tx][ty + i * 8];
}

// ---------------- flash attention ----------------
// 512 blocks x 4 waves: one 64-row q-tile per block, wave w owns 16 rows.
// Complement scheduling: blocks [0,256) carry big tiles (j=15-jx), blocks
// [256,512) the small (j=jx); same (bh,jx) -> paired work sums to ~17 tiles.
// All 512 blocks co-resident (46KB LDS -> 2 blocks/CU, 8 waves/CU).
// K from fused, V^T from vtg, both b128-staged, double-buffered, reg-prefetch.

__global__ __launch_bounds__(256) void k_attn(const short* __restrict__ fused,
                                              const short* __restrict__ vtg,
                                              short* __restrict__ outp) {
  const int id = blockIdx.x;
  const int phase = id >> 8;               // 0 big, 1 small
  const int v = id & 255;
  const int bh = (v & 7) + 8 * ((v >> 3) & 3);
  const int jx = v >> 5;                   // 0..7
  const int j = phase ? jx : (15 - jx);    // 64-row tile index 0..15
  const int b = bh >> 4, h = bh & 15;
  const int tid = threadIdx.x, lane = tid & 63, w = tid >> 6;
  const int l15 = lane & 15, lg = lane >> 4;
  const int q0 = j * 64;
  const int nkv = j + 1;

  __shared__ short Kl[2][64 * 72];
  __shared__ short Vt[2][64 * 72];     // V^T: [dh][s]
  __shared__ short Pl[4][16 * 72];     // wave-private P
  const short* base = fused + (size_t)b * 1024 * 4480;
  const short* vbase = vtg + (size_t)bh * 64 * 1024;
  short* op = outp + (size_t)b * 1024 * 1024;

  // staging coords: unit e -> row e>>3, col8 (e&7)*8 (b128 LDS writes)
  const int e0 = tid, e1 = tid + 256;
  const int r0e = e0 >> 3, c0e = (e0 & 7) << 3;
  const int r1e = e1 >> 3, c1e = (e1 & 7) << 3;

  s16x8 qf[2];
#pragma unroll
  for (int ks = 0; ks < 2; ks++)
    qf[ks] = *(const s16x8*)&base[(size_t)(q0 + w * 16 + l15) * 4480 +
                                  h * 64 + ks * 32 + lg * 8];

  f32x4 O[4] = {};
  float m_run[4], l_run[4];
#pragma unroll
  for (int r = 0; r < 4; r++) { m_run[r] = -1e30f; l_run[r] = 0.f; }

  {  // stage tile 0 -> buf 0
    s16x8 ka = *(const s16x8*)&base[(size_t)r0e * 4480 + 1024 + h * 64 + c0e];
    s16x8 kb = *(const s16x8*)&base[(size_t)r1e * 4480 + 1024 + h * 64 + c1e];
    s16x8 va = *(const s16x8*)&vbase[(size_t)r0e * 1024 + c0e];
    s16x8 vb = *(const s16x8*)&vbase[(size_t)r1e * 1024 + c1e];
    *(s16x8*)&Kl[0][r0e * 72 + c0e] = ka;
    *(s16x8*)&Kl[0][r1e * 72 + c1e] = kb;
    *(s16x8*)&Vt[0][r0e * 72 + c0e] = va;
    *(s16x8*)&Vt[0][r1e * 72 + c1e] = vb;
  }
  __syncthreads();

  for (int kt = 0; kt < nkv; kt++) {
    const int cur = kt & 1;
    const int kv0 = kt * 64;
    const bool pf = (kt + 1 < nkv);
    s16x8 kn0, kn1, vn0, vn1;
    if (pf) {
      const int kvn = kv0 + 64;
      kn0 = *(const s16x8*)&base[(size_t)(kvn + r0e) * 4480 + 1024 + h * 64 + c0e];
      kn1 = *(const s16x8*)&base[(size_t)(kvn + r1e) * 4480 + 1024 + h * 64 + c1e];
      vn0 = *(const s16x8*)&vbase[(size_t)r0e * 1024 + kvn + c0e];
      vn1 = *(const s16x8*)&vbase[(size_t)r1e * 1024 + kvn + c1e];
    }

    // S = Q @ K^T
    f32x4 S[4] = {};
    __builtin_amdgcn_s_setprio(1);
#pragma unroll
    for (int sf = 0; sf < 4; sf++) {
      s16x8 kf0 = *(const s16x8*)&Kl[cur][(sf * 16 + l15) * 72 + lg * 8];
      s16x8 kf1 = *(const s16x8*)&Kl[cur][(sf * 16 + l15) * 72 + 32 + lg * 8];
      S[sf] = mfma_bf16(qf[0], kf0, S[sf]);
      S[sf] = mfma_bf16(qf[1], kf1, S[sf]);
    }
    __builtin_amdgcn_s_setprio(0);

    const bool diag = (kt == j);
    float sv[4][4];
#pragma unroll
    for (int sf = 0; sf < 4; sf++)
#pragma unroll
      for (int r = 0; r < 4; r++) {
        float vv = S[sf][r] * 0.125f;
        if (diag) {
          const int sg = kv0 + sf * 16 + l15;
          const int qg = q0 + w * 16 + lg * 4 + r;
          if (sg > qg) vv = -1e30f;
        }
        sv[sf][r] = vv;
      }
#pragma unroll
    for (int r = 0; r < 4; r++) {
      float pm = fmaxf(fmaxf(sv[0][r], sv[1][r]), fmaxf(sv[2][r], sv[3][r]));
      pm = fmaxf(pm, __shfl_xor(pm, 1, 64));
      pm = fmaxf(pm, __shfl_xor(pm, 2, 64));
      pm = fmaxf(pm, __shfl_xor(pm, 4, 64));
      pm = fmaxf(pm, __shfl_xor(pm, 8, 64));
      const float mn = fmaxf(m_run[r], pm);
      const float fac = exp2f((m_run[r] - mn) * LOG2E);
      m_run[r] = mn;
      float rs = 0.f;
#pragma unroll
      for (int sf = 0; sf < 4; sf++) {
        float p = (sv[sf][r] <= -1e29f) ? 0.f : exp2f((sv[sf][r] - mn) * LOG2E);
        rs += p;
        Pl[w][(lg * 4 + r) * 72 + sf * 16 + l15] = f2bf(p);
      }
      rs += __shfl_xor(rs, 1, 64);
      rs += __shfl_xor(rs, 2, 64);
      rs += __shfl_xor(rs, 4, 64);
      rs += __shfl_xor(rs, 8, 64);
      l_run[r] = l_run[r] * fac + rs;
#pragma unroll
      for (int nf = 0; nf < 4; nf++) O[nf][r] *= fac;
    }

    // O += P @ V
    __builtin_amdgcn_s_setprio(1);
#pragma unroll
    for (int ks = 0; ks < 2; ks++) {
      s16x8 pfr = *(const s16x8*)&Pl[w][l15 * 72 + ks * 32 + lg * 8];
#pragma unroll
      for (int nf = 0; nf < 4; nf++) {
        s16x8 vf = *(const s16x8*)&Vt[cur][(nf * 16 + l15) * 72 + ks * 32 + lg * 8];
        O[nf] = mfma_bf16(pfr, vf, O[nf]);
      }
    }
    __builtin_amdgcn_s_setprio(0);

    __syncthreads();
    if (pf) {
      const int nxt = cur ^ 1;
      *(s16x8*)&Kl[nxt][r0e * 72 + c0e] = kn0;
      *(s16x8*)&Kl[nxt][r1e * 72 + c1e] = kn1;
      *(s16x8*)&Vt[nxt][r0e * 72 + c0e] = vn0;
      *(s16x8*)&Vt[nxt][r1e * 72 + c1e] = vn1;
      __syncthreads();
    }
  }

#pragma unroll
  for (int nf = 0; nf < 4; nf++)
#pragma unroll
    for (int r = 0; r < 4; r++) {
      const int row = q0 + w * 16 + lg * 4 + r;
      op[(size_t)row * 1024 + h * 64 + nf * 16 + l15] = f2bf(O[nf][r] / l_run[r]);
    }
}

// ---------------- Plucker lines ----------------

__device__ __forceinline__ void exterior6(const float p1[4], const float p2[4], float L[6]) {
  L[0] = p1[0] * p2[1] - p1[1] * p2[0];
  L[1] = p1[0] * p2[2] - p1[2] * p2[0];
  L[2] = p1[0] * p2[3] - p1[3] * p2[0];
  L[3] = p1[1] * p2[2] - p1[2] * p2[1];
  L[4] = p1[1] * p2[3] - p1[3] * p2[1];
  L[5] = p1[2] * p2[3] - p1[3] * p2[2];
  float n = sqrtf(L[0] * L[0] + L[1] * L[1] + L[2] * L[2] +
                  L[3] * L[3] + L[4] * L[4] + L[5] * L[5]);
  float inv = 1.f / fmaxf(n, 1e-12f);
#pragma unroll
  for (int j = 0; j < 6; j++) L[j] *= inv;
}

// jw layout: SoA [bh][6][1024]; rl layout: AoS [bh][t][6]
__global__ void k_lines(const float* __restrict__ proj, const float* __restrict__ Jm,
                        float* __restrict__ jw, float* __restrict__ rl) {
  const int idx = blockIdx.x * 256 + threadIdx.x;  // 32768
  const int t = idx & 1023, h = (idx >> 10) & 15, b = idx >> 14;
  const int n = b * 1024 + t;
  const int bh = b * 16 + h;
  float p1[4], p2[4], L[6];
#pragma unroll
  for (int p = 0; p < 4; p++) {
    float a  = (t >= 2) ? proj[(size_t)(n - 2) * 384 + h * 4 + p] : 0.f;
    float bb = (t >= 1) ? proj[(size_t)(n - 1) * 384 + 64 + h * 4 + p] : 0.f;
    p1[p] = a + bb;
    p2[p] = proj[(size_t)n * 384 + 128 + h * 4 + p];
  }
  exterior6(p1, p2, L);
  const size_t jo = (size_t)bh * 6144 + t;
#pragma unroll
  for (int j = 0; j < 6; j++) {
    float s = 0.f;
#pragma unroll
    for (int i = 0; i < 6; i++) s += L[i] * Jm[i * 6 + j];
    jw[jo + (size_t)j * 1024] = s;
  }
#pragma unroll
  for (int p = 0; p < 4; p++) {
    p1[p] = proj[(size_t)n * 384 + 192 + h * 4 + p];
    p2[p] = proj[(size_t)n * 384 + 256 + h * 4 + p];
  }
  exterior6(p1, p2, L);
  const size_t ro = ((size_t)bh * 1024 + t) * 6;
#pragma unroll
  for (int j = 0; j < 6; j++) rl[ro + j] = L[j];
}

// ---------------- decayed memory score ----------------

__global__ __launch_bounds__(256) void k_mscore(const float* __restrict__ jw,
                                                const float* __restrict__ rl,
                                                const float* __restrict__ dlog,
                                                float* __restrict__ ms) {
  const int gtid = blockIdx.x * 256 + threadIdx.x;
  const int wid = gtid >> 6, lane = gtid & 63;
  const int bh = wid >> 10, t = wid & 1023;
  const int h = bh & 15, b = bh >> 4;
  const float d = 1.f / (1.f + expf(-dlog[h]));
  const float l2d = log2f(d);
  const float* jwp = jw + (size_t)bh * 6144;
  const float* rp = rl + ((size_t)bh * 1024 + t) * 6;
  const float r0 = rp[0], r1 = rp[1], r2 = rp[2], r3 = rp[3], r4 = rp[4], r5 = rp[5];
  float wgt = exp2f((float)(t - lane) * l2d);
  const float gw = exp2f(-64.f * l2d);
  float acc = 0.f;
  for (int s = lane; s < t; s += 64) {
    const float dot = r0 * jwp[s] + r1 * jwp[1024 + s] + r2 * jwp[2048 + s] +
                      r3 * jwp[3072 + s] + r4 * jwp[4096 + s] + r5 * jwp[5120 + s];
    acc += wgt * dot * dot;
    wgt *= gw;
  }
  acc += __shfl_xor(acc, 1, 64);
  acc += __shfl_xor(acc, 2, 64);
  acc += __shfl_xor(acc, 4, 64);
  acc += __shfl_xor(acc, 8, 64);
  acc += __shfl_xor(acc, 16, 64);
  acc += __shfl_xor(acc, 32, 64);
  if (lane == 0) ms[((size_t)(b * 1024 + t)) * 16 + h] = acc;
}

// ---------------- combine: comb = bf16(attn + gated*mem_val) ----------------

__global__ __launch_bounds__(256) void k_combine(const short* __restrict__ attn,
                                                 const short* __restrict__ fused,
                                                 const float* __restrict__ proj,
                                                 const float* __restrict__ ms,
                                                 const float* __restrict__ mem_scale,
                                                 const float* __restrict__ gate_b,
                                                 short* __restrict__ comb) {
  const int n = blockIdx.x;
  const int tid = threadIdx.x;
  __shared__ float gsh;
  if (tid < 16) {
    const float gp = proj[(size_t)n * 384 + 320 + tid] + gate_b[tid];
    const float g = 1.f / (1.f + expf(-gp));
    const float sc = ms[(size_t)n * 16 + tid] * mem_scale[tid];
    const float sg = 1.f / (1.f + expf(-sc));
    float v = sg * g;
    v += __shfl_xor(v, 1, 64);
    v += __shfl_xor(v, 2, 64);
    v += __shfl_xor(v, 4, 64);
    v += __shfl_xor(v, 8, 64);
    if (tid == 0) gsh = v * (1.f / 16.f);
  }
  __syncthreads();
  const float g = gsh;
  const int c0 = tid * 4;
  short4 av = *(const short4*)&attn[(size_t)n * 1024 + c0];
  short4 mvv = *(const short4*)&fused[(size_t)n * 4480 + 3072 + c0];
  short4 ov;
  ov.x = f2bf(bf2f(av.x) + g * bf2f(mvv.x));
  ov.y = f2bf(bf2f(av.y) + g * bf2f(mvv.y));
  ov.z = f2bf(bf2f(av.z) + g * bf2f(mvv.z));
  ov.w = f2bf(bf2f(av.w) + g * bf2f(mvv.w));
  *(short4*)&comb[(size_t)n * 1024 + c0] = ov;
}

// ---------------------------------------------------------------------------

extern "C" void kernel_launch(void* const* d_in, const int* in_sizes, int n_in,
                              void* d_out, int out_size, void* d_ws, size_t ws_size,
                              hipStream_t stream) {
  const float* x    = (const float*)d_in[0];
  const float* qkvw = (const float*)d_in[1];
  const float* qkvb = (const float*)d_in[2];
  const float* w1w  = (const float*)d_in[3];
  const float* w2w  = (const float*)d_in[4];
  const float* r1w  = (const float*)d_in[5];
  const float* r2w  = (const float*)d_in[6];
  const float* mvw  = (const float*)d_in[7];
  const float* mvb  = (const float*)d_in[8];
  const float* gw   = (const float*)d_in[9];
  const float* gb   = (const float*)d_in[10];
  const float* msc  = (const float*)d_in[11];
  const float* ow   = (const float*)d_in[12];
  const float* ob   = (const float*)d_in[13];
  const float* dlog = (const float*)d_in[14];
  const float* Jm   = (const float*)d_in[15];
  float* out = (float*)d_out;

  char* wsp = (char*)d_ws;
  auto alloc = [&](size_t bytes) {
    char* p = wsp;
    wsp += (bytes + 255) & ~(size_t)255;
    return p;
  };
  short* xb     = (short*)alloc((size_t)2048 * 1024 * 2);
  short* btall  = (short*)alloc((size_t)4480 * 1024 * 2);
  short* owT    = (short*)alloc((size_t)1024 * 1024 * 2);
  short* fusedC = (short*)alloc((size_t)2048 * 4480 * 2);
  float* projf  = (float*)alloc((size_t)2048 * 384 * 4);
  float* biasA  = (float*)alloc((size_t)4480 * 4);
  short* vtg    = (short*)alloc((size_t)32 * 64 * 1024 * 2);
  short* attnO  = (short*)alloc((size_t)2048 * 1024 * 2);
  short* comb   = (short*)alloc((size_t)2048 * 1024 * 2);
  float* jwb    = (float*)alloc((size_t)32 * 6144 * 4);
  float* rlb    = (float*)alloc((size_t)32768 * 6 * 4);
  float* msb    = (float*)alloc((size_t)2048 * 16 * 4);

  k_cvt<<<2048, 256, 0, stream>>>(x, xb, 2048 * 1024);
  dim3 tb(32, 8);
  k_tconv<<<dim3(96, 32), tb, 0, stream>>>(qkvw, btall, 1024, 3072);
  k_tconv<<<dim3(32, 32), tb, 0, stream>>>(mvw, btall + (size_t)3072 * 1024, 1024, 1024);
  k_tconv<<<dim3(32, 32), tb, 0, stream>>>(ow, owT, 1024, 1024);
  k_smallw<<<1554, 256, 0, stream>>>(w1w, w2w, r1w, r2w, gw, qkvb, mvb,
                                     btall + (size_t)4096 * 1024, biasA);

  k_gemmF<<<dim3(16, 35), 256, 0, stream>>>(xb, btall, fusedC, biasA, projf);

  k_vtr<<<dim3(32, 2, 32), tb, 0, stream>>>(fusedC, vtg);
  k_attn<<<512, 256, 0, stream>>>(fusedC, vtg, attnO);

  k_lines<<<128, 256, 0, stream>>>(projf, Jm, jwb, rlb);
  k_mscore<<<8192, 256, 0, stream>>>(jwb, rlb, dlog, msb);
  k_combine<<<2048, 256, 0, stream>>>(attnO, fusedC, projf, msb, msc, gb, comb);

  k_gemm<<<dim3(16, 8), 256, 0, stream>>>(comb, owT, out, ob, 1024, 1024);
}

// Round 8
// 135.880 us; speedup vs baseline: 1.2371x; 1.0577x over previous
//
#include <hip/hip_runtime.h>
#include <hip/hip_bf16.h>
#include <stdint.h>

// ---------------------------------------------------------------------------
// TrigramWriteMemoryAttention  (B=2, T=1024, D=1024, H=16, dh=64, pd=4)
// Fused buffer layout (bf16, row stride 4480):
//   cols 0:1024 Q | 1024:2048 K | 2048:3072 V | 3072:4096 mem_val | 4096:4480 small
// small cols (also written f32 to projf[2048][384]):
//   0:64 xw1a | 64:128 xw1b | 128:192 w2 | 192:256 r1 | 256:320 r2 | 320:336 gate
// ---------------------------------------------------------------------------

typedef __attribute__((ext_vector_type(8))) __bf16 bf16v8;
typedef __attribute__((ext_vector_type(8))) short  s16x8;
typedef __attribute__((ext_vector_type(4))) float  f32x4;

#define LOG2E 1.4426950408889634f

__device__ __forceinline__ float bf2f(short s) {
  union { uint32_t u; float f; } cv; cv.u = ((uint32_t)(uint16_t)s) << 16; return cv.f;
}
__device__ __forceinline__ short f2bf(float f) {
  union { float f; uint32_t u; } cv; cv.f = f;
  uint32_t r = cv.u + 0x7fffu + ((cv.u >> 16) & 1u);
  return (short)(r >> 16);
}

__device__ __forceinline__ f32x4 mfma_bf16(s16x8 a, s16x8 b, f32x4 c) {
  return __builtin_amdgcn_mfma_f32_16x16x32_bf16(
      __builtin_bit_cast(bf16v8, a), __builtin_bit_cast(bf16v8, b), c, 0, 0, 0);
}

__device__ __forceinline__ void gload_lds16(const void* g, void* l) {
  __builtin_amdgcn_global_load_lds(
      (const __attribute__((address_space(1))) uint32_t*)g,
      (__attribute__((address_space(3))) uint32_t*)l, 16, 0, 0);
}

// ---------------- fused prep: cvt + 3x transposed weight conv + smallw + bias
// grid 8722 x 256.  Block ranges:
//   [0,2048)      cvt x -> xb (bf16)
//   [2048,5120)   qkvw^T   -> btall[0:3072]      (96 x 32 tiles)
//   [5120,6144)   mvw^T    -> btall[3072:4096]   (32 x 32 tiles)
//   [6144,7168)   ow^T     -> owT               (32 x 32 tiles)
//   [7168,8704)   small weights -> btall[4096:4480]
//   [8704,8722)   biasAll

__global__ __launch_bounds__(256) void k_prep(
    const float* __restrict__ x, const float* __restrict__ qkvw,
    const float* __restrict__ mvw, const float* __restrict__ ow,
    const float* __restrict__ w1w, const float* __restrict__ w2w,
    const float* __restrict__ r1w, const float* __restrict__ r2w,
    const float* __restrict__ gw, const float* __restrict__ qkvb,
    const float* __restrict__ mvb,
    short* __restrict__ xb, short* __restrict__ btall, short* __restrict__ owT,
    float* __restrict__ biasAll) {
  __shared__ float tile[32][33];
  const int bid = blockIdx.x;
  const int tid = threadIdx.x;
  if (bid < 2048) {  // cvt
    const int i = (bid * 256 + tid) * 4;
    float4 v = *(const float4*)&x[i];
    short4 o;
    o.x = f2bf(v.x); o.y = f2bf(v.y); o.z = f2bf(v.z); o.w = f2bf(v.w);
    *(short4*)&xb[i] = o;
    return;
  }
  if (bid < 7168) {  // transposed conversions
    const float* W; short* Wt; int N, u;
    if (bid < 5120)      { W = qkvw; Wt = btall;                       N = 3072; u = bid - 2048; }
    else if (bid < 6144) { W = mvw;  Wt = btall + (size_t)3072 * 1024; N = 1024; u = bid - 5120; }
    else                 { W = ow;   Wt = owT;                         N = 1024; u = bid - 6144; }
    const int ntiles = N >> 5;
    const int n0 = (u % ntiles) * 32, k0 = (u / ntiles) * 32;
    const int tx = tid & 31, ty = tid >> 5;  // 32x8
#pragma unroll
    for (int i = 0; i < 4; i++)
      tile[ty + i * 8][tx] = W[(size_t)(k0 + ty + i * 8) * N + n0 + tx];
    __syncthreads();
#pragma unroll
    for (int i = 0; i < 4; i++)
      Wt[(size_t)(n0 + ty + i * 8) * 1024 + k0 + tx] = f2bf(tile[tx][ty + i * 8]);
    return;
  }
  if (bid < 8704) {  // small weights
    const int idx = (bid - 7168) * 256 + tid;  // 384*1024
    const int r = idx >> 10, k = idx & 1023;
    float v = 0.f;
    if (r < 64)       v = w1w[(size_t)k * 64 + r];
    else if (r < 128) v = w1w[(size_t)(1024 + k) * 64 + (r - 64)];
    else if (r < 192) v = w2w[(size_t)k * 64 + (r - 128)];
    else if (r < 256) v = r1w[(size_t)k * 64 + (r - 192)];
    else if (r < 320) v = r2w[(size_t)k * 64 + (r - 256)];
    else if (r < 336) v = gw[(size_t)k * 16 + (r - 320)];
    btall[(size_t)4096 * 1024 + idx] = f2bf(v);
    return;
  }
  {  // bias
    const int i = (bid - 8704) * 256 + tid;
    if (i < 4480) {
      float v = 0.f;
      if (i < 3072) v = qkvb[i];
      else if (i < 4096) v = mvb[i - 3072];
      biasAll[i] = v;
    }
  }
}

// ---------------- fused projection GEMM ----------------
// C[2048][4480] = xb @ btall^T + biasAll; proj cols (>=4096) go to projf f32.

__global__ __launch_bounds__(256) void k_gemmF(const short* __restrict__ A,
                                               const short* __restrict__ Bt,
                                               short* __restrict__ C,
                                               const float* __restrict__ bias,
                                               float* __restrict__ projf) {
  const int N = 4480, K = 1024;
  __shared__ short As[128 * 32];
  __shared__ short Bs[128 * 32];
  const int m0 = blockIdx.x * 128, n0 = blockIdx.y * 128;
  const int tid = threadIdx.x;
  const int lane = tid & 63, w = tid >> 6;
  const int wr = (w >> 1) * 64, wc = (w & 1) * 64;
  const int l15 = lane & 15, lg = lane >> 4;
  f32x4 acc[4][4] = {};
  for (int k0 = 0; k0 < K; k0 += 32) {
#pragma unroll
    for (int p = 0; p < 2; p++) {
      const int e = p * 256 + tid;
      const int r = e >> 2, c8 = (e & 3) << 3;
      gload_lds16(A + (size_t)(m0 + r) * K + k0 + c8, As + e * 8);
      gload_lds16(Bt + (size_t)(n0 + r) * K + k0 + c8, Bs + e * 8);
    }
    __syncthreads();
    s16x8 af[4], bfv[4];
#pragma unroll
    for (int i = 0; i < 4; i++) {
      af[i]  = *(const s16x8*)&As[(wr + i * 16 + l15) * 32 + lg * 8];
      bfv[i] = *(const s16x8*)&Bs[(wc + i * 16 + l15) * 32 + lg * 8];
    }
#pragma unroll
    for (int mi = 0; mi < 4; mi++)
#pragma unroll
      for (int ni = 0; ni < 4; ni++)
        acc[mi][ni] = mfma_bf16(af[mi], bfv[ni], acc[mi][ni]);
    __syncthreads();
  }
  const bool isproj = (n0 >= 4096);
#pragma unroll
  for (int mi = 0; mi < 4; mi++)
#pragma unroll
    for (int ni = 0; ni < 4; ni++) {
      const int col = n0 + wc + ni * 16 + l15;
      const float bv = bias[col];
#pragma unroll
      for (int r = 0; r < 4; r++) {
        const int row = m0 + wr + mi * 16 + lg * 4 + r;
        const float v = acc[mi][ni][r] + bv;
        if (isproj) projf[(size_t)row * 384 + (col - 4096)] = v;
        else        C[(size_t)row * 4480 + col] = f2bf(v);
      }
    }
}

// ---------------- generic GEMM (out-projection) ----------------

__global__ __launch_bounds__(256) void k_gemm(const short* __restrict__ A,
                                              const short* __restrict__ Bt,
                                              float* __restrict__ C,
                                              const float* __restrict__ bias,
                                              int N, int K) {
  __shared__ short As[128 * 32];
  __shared__ short Bs[128 * 32];
  const int m0 = blockIdx.x * 128, n0 = blockIdx.y * 128;
  const int tid = threadIdx.x;
  const int lane = tid & 63, w = tid >> 6;
  const int wr = (w >> 1) * 64, wc = (w & 1) * 64;
  const int l15 = lane & 15, lg = lane >> 4;
  f32x4 acc[4][4] = {};
  for (int k0 = 0; k0 < K; k0 += 32) {
#pragma unroll
    for (int p = 0; p < 2; p++) {
      const int e = p * 256 + tid;
      const int r = e >> 2, c8 = (e & 3) << 3;
      gload_lds16(A + (size_t)(m0 + r) * K + k0 + c8, As + e * 8);
      gload_lds16(Bt + (size_t)(n0 + r) * K + k0 + c8, Bs + e * 8);
    }
    __syncthreads();
    s16x8 af[4], bfv[4];
#pragma unroll
    for (int i = 0; i < 4; i++) {
      af[i]  = *(const s16x8*)&As[(wr + i * 16 + l15) * 32 + lg * 8];
      bfv[i] = *(const s16x8*)&Bs[(wc + i * 16 + l15) * 32 + lg * 8];
    }
#pragma unroll
    for (int mi = 0; mi < 4; mi++)
#pragma unroll
      for (int ni = 0; ni < 4; ni++)
        acc[mi][ni] = mfma_bf16(af[mi], bfv[ni], acc[mi][ni]);
    __syncthreads();
  }
#pragma unroll
  for (int mi = 0; mi < 4; mi++)
#pragma unroll
    for (int ni = 0; ni < 4; ni++) {
      const int col = n0 + wc + ni * 16 + l15;
      const float bv = bias ? bias[col] : 0.f;
#pragma unroll
      for (int r = 0; r < 4; r++) {
        const int row = m0 + wr + mi * 16 + lg * 4 + r;
        C[(size_t)row * N + col] = acc[mi][ni][r] + bv;
      }
    }
}

// ---------------- V transpose: fused V cols -> vtg[bh][64][1024] ----------------

__global__ void k_vtr(const short* __restrict__ fused, short* __restrict__ vtg) {
  __shared__ short tile[32][33];
  const int bh = blockIdx.z;
  const int b = bh >> 4, h = bh & 15;
  const int t0 = blockIdx.x * 32, d0 = blockIdx.y * 32;
  const int tx = threadIdx.x, ty = threadIdx.y;  // 32x8
#pragma unroll
  for (int i = 0; i < 4; i++)
    tile[ty + i * 8][tx] =
        fused[(size_t)(b * 1024 + t0 + ty + i * 8) * 4480 + 2048 + h * 64 + d0 + tx];
  __syncthreads();
#pragma unroll
  for (int i = 0; i < 4; i++)
    vtg[(size_t)(bh * 64 + d0 + ty + i * 8) * 1024 + t0 + tx] = tile[tx][ty + i * 8];
}

// ---------------- flash attention, kv-split 2-way ----------------
// 1024 blocks x 4 waves: id -> j = 15-(id>>6) (LPT descending), rem = id&63,
// sid = rem>>5, bh = rem&31 (bh%8 == id%8 -> XCD-pinned heads).
// Block handles q-tile j (64 rows, wave w owns 16) over kv-tiles [lo,hi):
// sid0 [0,half), sid1 [half,nkv).  Single-buffer LDS (27.6KB -> 4 blocks/CU
// = 16 waves/CU), stage-late: loads issued before compute, LDS written after
// the post-compute barrier.  Unnormalized O + (m,l) partials to scratch;
// k_amerge combines.  T13 defer-max (THR=8).

__global__ __launch_bounds__(256) void k_attn(const short* __restrict__ fused,
                                              const short* __restrict__ vtg,
                                              float* __restrict__ Of,
                                              float* __restrict__ Ml) {
  const int id = blockIdx.x;
  const int j = 15 - (id >> 6);
  const int rem = id & 63;
  const int sid = rem >> 5, bh = rem & 31;
  const int b = bh >> 4, h = bh & 15;
  const int tid = threadIdx.x, lane = tid & 63, w = tid >> 6;
  const int l15 = lane & 15, lg = lane >> 4;
  const int q0 = j * 64;
  const int nkv = j + 1;
  const int half = (nkv + 1) >> 1;
  const int lo = sid ? half : 0;
  const int hi = sid ? nkv : half;
  const int pidx = ((j * 32 + bh) << 1) | sid;

  __shared__ short Kl[64 * 72];
  __shared__ short Vt[64 * 72];        // V^T: [dh][s]
  __shared__ short Pl[4][16 * 72];     // wave-private P
  const short* base = fused + (size_t)b * 1024 * 4480;
  const short* vbase = vtg + (size_t)bh * 64 * 1024;

  // staging coords: unit e -> row e>>3, col8 (e&7)*8 (b128 LDS writes)
  const int e0 = tid, e1 = tid + 256;
  const int r0e = e0 >> 3, c0e = (e0 & 7) << 3;
  const int r1e = e1 >> 3, c1e = (e1 & 7) << 3;

  s16x8 qf[2];
#pragma unroll
  for (int ks = 0; ks < 2; ks++)
    qf[ks] = *(const s16x8*)&base[(size_t)(q0 + w * 16 + l15) * 4480 +
                                  h * 64 + ks * 32 + lg * 8];

  f32x4 O[4] = {};
  float m_run[4], l_run[4];
#pragma unroll
  for (int r = 0; r < 4; r++) { m_run[r] = -1e30f; l_run[r] = 0.f; }

  if (lo < hi) {  // stage tile lo
    const int kv0 = lo * 64;
    s16x8 ka = *(const s16x8*)&base[(size_t)(kv0 + r0e) * 4480 + 1024 + h * 64 + c0e];
    s16x8 kb = *(const s16x8*)&base[(size_t)(kv0 + r1e) * 4480 + 1024 + h * 64 + c1e];
    s16x8 va = *(const s16x8*)&vbase[(size_t)r0e * 1024 + kv0 + c0e];
    s16x8 vb = *(const s16x8*)&vbase[(size_t)r1e * 1024 + kv0 + c1e];
    *(s16x8*)&Kl[r0e * 72 + c0e] = ka;
    *(s16x8*)&Kl[r1e * 72 + c1e] = kb;
    *(s16x8*)&Vt[r0e * 72 + c0e] = va;
    *(s16x8*)&Vt[r1e * 72 + c1e] = vb;
  }
  __syncthreads();

  for (int kt = lo; kt < hi; kt++) {
    const int kv0 = kt * 64;
    const bool pf = (kt + 1 < hi);
    s16x8 kn0, kn1, vn0, vn1;
    if (pf) {
      const int kvn = kv0 + 64;
      kn0 = *(const s16x8*)&base[(size_t)(kvn + r0e) * 4480 + 1024 + h * 64 + c0e];
      kn1 = *(const s16x8*)&base[(size_t)(kvn + r1e) * 4480 + 1024 + h * 64 + c1e];
      vn0 = *(const s16x8*)&vbase[(size_t)r0e * 1024 + kvn + c0e];
      vn1 = *(const s16x8*)&vbase[(size_t)r1e * 1024 + kvn + c1e];
    }

    // S = Q @ K^T
    f32x4 S[4] = {};
    __builtin_amdgcn_s_setprio(1);
#pragma unroll
    for (int sf = 0; sf < 4; sf++) {
      s16x8 kf0 = *(const s16x8*)&Kl[(sf * 16 + l15) * 72 + lg * 8];
      s16x8 kf1 = *(const s16x8*)&Kl[(sf * 16 + l15) * 72 + 32 + lg * 8];
      S[sf] = mfma_bf16(qf[0], kf0, S[sf]);
      S[sf] = mfma_bf16(qf[1], kf1, S[sf]);
    }
    __builtin_amdgcn_s_setprio(0);

    const bool diag = (kt == j);
    float sv[4][4];
#pragma unroll
    for (int sf = 0; sf < 4; sf++)
#pragma unroll
      for (int r = 0; r < 4; r++) {
        float vv = S[sf][r] * 0.125f;
        if (diag) {
          const int sg = kv0 + sf * 16 + l15;
          const int qg = q0 + w * 16 + lg * 4 + r;
          if (sg > qg) vv = -1e30f;
        }
        sv[sf][r] = vv;
      }
#pragma unroll
    for (int r = 0; r < 4; r++) {
      float pm = fmaxf(fmaxf(sv[0][r], sv[1][r]), fmaxf(sv[2][r], sv[3][r]));
      pm = fmaxf(pm, __shfl_xor(pm, 1, 64));
      pm = fmaxf(pm, __shfl_xor(pm, 2, 64));
      pm = fmaxf(pm, __shfl_xor(pm, 4, 64));
      pm = fmaxf(pm, __shfl_xor(pm, 8, 64));
      if (pm > m_run[r] + 8.f) {  // T13 defer-max
        const float fac = exp2f((m_run[r] - pm) * LOG2E);
        m_run[r] = pm;
        l_run[r] *= fac;
#pragma unroll
        for (int nf = 0; nf < 4; nf++) O[nf][r] *= fac;
      }
      float rs = 0.f;
#pragma unroll
      for (int sf = 0; sf < 4; sf++) {
        float p = (sv[sf][r] <= -1e29f) ? 0.f : exp2f((sv[sf][r] - m_run[r]) * LOG2E);
        rs += p;
        Pl[w][(lg * 4 + r) * 72 + sf * 16 + l15] = f2bf(p);
      }
      rs += __shfl_xor(rs, 1, 64);
      rs += __shfl_xor(rs, 2, 64);
      rs += __shfl_xor(rs, 4, 64);
      rs += __shfl_xor(rs, 8, 64);
      l_run[r] += rs;
    }

    // O += P @ V
    __builtin_amdgcn_s_setprio(1);
#pragma unroll
    for (int ks = 0; ks < 2; ks++) {
      s16x8 pfr = *(const s16x8*)&Pl[w][l15 * 72 + ks * 32 + lg * 8];
#pragma unroll
      for (int nf = 0; nf < 4; nf++) {
        s16x8 vf = *(const s16x8*)&Vt[(nf * 16 + l15) * 72 + ks * 32 + lg * 8];
        O[nf] = mfma_bf16(pfr, vf, O[nf]);
      }
    }
    __builtin_amdgcn_s_setprio(0);

    __syncthreads();
    if (pf) {
      *(s16x8*)&Kl[r0e * 72 + c0e] = kn0;
      *(s16x8*)&Kl[r1e * 72 + c1e] = kn1;
      *(s16x8*)&Vt[r0e * 72 + c0e] = vn0;
      *(s16x8*)&Vt[r1e * 72 + c1e] = vn1;
      __syncthreads();
    }
  }

  // write partials (unnormalized O + m,l)
  float* ob = Of + (size_t)pidx * 4096;
  float* mb = Ml + (size_t)pidx * 128;
#pragma unroll
  for (int r = 0; r < 4; r++) {
    const int rloc = w * 16 + lg * 4 + r;
#pragma unroll
    for (int nf = 0; nf < 4; nf++)
      ob[rloc * 64 + nf * 16 + l15] = O[nf][r];
    if (l15 == 0) {
      mb[rloc] = m_run[r];
      mb[64 + rloc] = l_run[r];
    }
  }
}

// ---------------- attention merge: combine the 2 kv-split partials ----------

__global__ __launch_bounds__(256) void k_amerge(const float* __restrict__ Of,
                                                const float* __restrict__ Ml,
                                                short* __restrict__ outp) {
  const int g = blockIdx.x * 256 + threadIdx.x;   // 524288
  const int rg = g >> 4, c4 = (g & 15) << 2;
  const int p = rg >> 6, rloc = rg & 63;
  const int j = p >> 5, bh = p & 31;
  const int b = bh >> 4, h = bh & 15;
  const int t = j * 64 + rloc;
  const float* ml0 = Ml + (size_t)(p * 2 + 0) * 128;
  const float* ml1 = Ml + (size_t)(p * 2 + 1) * 128;
  const float m0 = ml0[rloc], l0 = ml0[64 + rloc];
  const float m1 = ml1[rloc], l1 = ml1[64 + rloc];
  const float M = fmaxf(m0, m1);
  const float w0 = exp2f((m0 - M) * LOG2E);
  const float w1 = exp2f((m1 - M) * LOG2E);
  const float inv = 1.f / (w0 * l0 + w1 * l1);
  f32x4 o0 = *(const f32x4*)&Of[(size_t)(p * 2 + 0) * 4096 + rloc * 64 + c4];
  f32x4 o1 = *(const f32x4*)&Of[(size_t)(p * 2 + 1) * 4096 + rloc * 64 + c4];
  short4 ov;
  ov.x = f2bf((w0 * o0[0] + w1 * o1[0]) * inv);
  ov.y = f2bf((w0 * o0[1] + w1 * o1[1]) * inv);
  ov.z = f2bf((w0 * o0[2] + w1 * o1[2]) * inv);
  ov.w = f2bf((w0 * o0[3] + w1 * o1[3]) * inv);
  *(short4*)&outp[((size_t)(b * 1024 + t)) * 1024 + h * 64 + c4] = ov;
}

// ---------------- Plucker lines ----------------

__device__ __forceinline__ void exterior6(const float p1[4], const float p2[4], float L[6]) {
  L[0] = p1[0] * p2[1] - p1[1] * p2[0];
  L[1] = p1[0] * p2[2] - p1[2] * p2[0];
  L[2] = p1[0] * p2[3] - p1[3] * p2[0];
  L[3] = p1[1] * p2[2] - p1[2] * p2[1];
  L[4] = p1[1] * p2[3] - p1[3] * p2[1];
  L[5] = p1[2] * p2[3] - p1[3] * p2[2];
  float n = sqrtf(L[0] * L[0] + L[1] * L[1] + L[2] * L[2] +
                  L[3] * L[3] + L[4] * L[4] + L[5] * L[5]);
  float inv = 1.f / fmaxf(n, 1e-12f);
#pragma unroll
  for (int j = 0; j < 6; j++) L[j] *= inv;
}

// jw layout: SoA [bh][6][1024]; rl layout: AoS [bh][t][6]
__global__ void k_lines(const float* __restrict__ proj, const float* __restrict__ Jm,
                        float* __restrict__ jw, float* __restrict__ rl) {
  const int idx = blockIdx.x * 256 + threadIdx.x;  // 32768
  const int t = idx & 1023, h = (idx >> 10) & 15, b = idx >> 14;
  const int n = b * 1024 + t;
  const int bh = b * 16 + h;
  float p1[4], p2[4], L[6];
#pragma unroll
  for (int p = 0; p < 4; p++) {
    float a  = (t >= 2) ? proj[(size_t)(n - 2) * 384 + h * 4 + p] : 0.f;
    float bb = (t >= 1) ? proj[(size_t)(n - 1) * 384 + 64 + h * 4 + p] : 0.f;
    p1[p] = a + bb;
    p2[p] = proj[(size_t)n * 384 + 128 + h * 4 + p];
  }
  exterior6(p1, p2, L);
  const size_t jo = (size_t)bh * 6144 + t;
#pragma unroll
  for (int j = 0; j < 6; j++) {
    float s = 0.f;
#pragma unroll
    for (int i = 0; i < 6; i++) s += L[i] * Jm[i * 6 + j];
    jw[jo + (size_t)j * 1024] = s;
  }
#pragma unroll
  for (int p = 0; p < 4; p++) {
    p1[p] = proj[(size_t)n * 384 + 192 + h * 4 + p];
    p2[p] = proj[(size_t)n * 384 + 256 + h * 4 + p];
  }
  exterior6(p1, p2, L);
  const size_t ro = ((size_t)bh * 1024 + t) * 6;
#pragma unroll
  for (int j = 0; j < 6; j++) rl[ro + j] = L[j];
}

// ---------------- decayed memory score ----------------

__global__ __launch_bounds__(256) void k_mscore(const float* __restrict__ jw,
                                                const float* __restrict__ rl,
                                                const float* __restrict__ dlog,
                                                float* __restrict__ ms) {
  const int gtid = blockIdx.x * 256 + threadIdx.x;
  const int wid = gtid >> 6, lane = gtid & 63;
  const int bh = wid >> 10, t = wid & 1023;
  const int h = bh & 15, b = bh >> 4;
  const float d = 1.f / (1.f + expf(-dlog[h]));
  const float l2d = log2f(d);
  const float* jwp = jw + (size_t)bh * 6144;
  const float* rp = rl + ((size_t)bh * 1024 + t) * 6;
  const float r0 = rp[0], r1 = rp[1], r2 = rp[2], r3 = rp[3], r4 = rp[4], r5 = rp[5];
  float wgt = exp2f((float)(t - lane) * l2d);
  const float gw = exp2f(-64.f * l2d);
  float acc = 0.f;
  for (int s = lane; s < t; s += 64) {
    const float dot = r0 * jwp[s] + r1 * jwp[1024 + s] + r2 * jwp[2048 + s] +
                      r3 * jwp[3072 + s] + r4 * jwp[4096 + s] + r5 * jwp[5120 + s];
    acc += wgt * dot * dot;
    wgt *= gw;
  }
  acc += __shfl_xor(acc, 1, 64);
  acc += __shfl_xor(acc, 2, 64);
  acc += __shfl_xor(acc, 4, 64);
  acc += __shfl_xor(acc, 8, 64);
  acc += __shfl_xor(acc, 16, 64);
  acc += __shfl_xor(acc, 32, 64);
  if (lane == 0) ms[((size_t)(b * 1024 + t)) * 16 + h] = acc;
}

// ---------------- combine: comb = bf16(attn + gated*mem_val) ----------------

__global__ __launch_bounds__(256) void k_combine(const short* __restrict__ attn,
                                                 const short* __restrict__ fused,
                                                 const float* __restrict__ proj,
                                                 const float* __restrict__ ms,
                                                 const float* __restrict__ mem_scale,
                                                 const float* __restrict__ gate_b,
                                                 short* __restrict__ comb) {
  const int n = blockIdx.x;
  const int tid = threadIdx.x;
  __shared__ float gsh;
  if (tid < 16) {
    const float gp = proj[(size_t)n * 384 + 320 + tid] + gate_b[tid];
    const float g = 1.f / (1.f + expf(-gp));
    const float sc = ms[(size_t)n * 16 + tid] * mem_scale[tid];
    const float sg = 1.f / (1.f + expf(-sc));
    float v = sg * g;
    v += __shfl_xor(v, 1, 64);
    v += __shfl_xor(v, 2, 64);
    v += __shfl_xor(v, 4, 64);
    v += __shfl_xor(v, 8, 64);
    if (tid == 0) gsh = v * (1.f / 16.f);
  }
  __syncthreads();
  const float g = gsh;
  const int c0 = tid * 4;
  short4 av = *(const short4*)&attn[(size_t)n * 1024 + c0];
  short4 mvv = *(const short4*)&fused[(size_t)n * 4480 + 3072 + c0];
  short4 ov;
  ov.x = f2bf(bf2f(av.x) + g * bf2f(mvv.x));
  ov.y = f2bf(bf2f(av.y) + g * bf2f(mvv.y));
  ov.z = f2bf(bf2f(av.z) + g * bf2f(mvv.z));
  ov.w = f2bf(bf2f(av.w) + g * bf2f(mvv.w));
  *(short4*)&comb[(size_t)n * 1024 + c0] = ov;
}

// ---------------------------------------------------------------------------

extern "C" void kernel_launch(void* const* d_in, const int* in_sizes, int n_in,
                              void* d_out, int out_size, void* d_ws, size_t ws_size,
                              hipStream_t stream) {
  const float* x    = (const float*)d_in[0];
  const float* qkvw = (const float*)d_in[1];
  const float* qkvb = (const float*)d_in[2];
  const float* w1w  = (const float*)d_in[3];
  const float* w2w  = (const float*)d_in[4];
  const float* r1w  = (const float*)d_in[5];
  const float* r2w  = (const float*)d_in[6];
  const float* mvw  = (const float*)d_in[7];
  const float* mvb  = (const float*)d_in[8];
  const float* gw   = (const float*)d_in[9];
  const float* gb   = (const float*)d_in[10];
  const float* msc  = (const float*)d_in[11];
  const float* ow   = (const float*)d_in[12];
  const float* ob   = (const float*)d_in[13];
  const float* dlog = (const float*)d_in[14];
  const float* Jm   = (const float*)d_in[15];
  float* out = (float*)d_out;

  char* wsp = (char*)d_ws;
  auto alloc = [&](size_t bytes) {
    char* p = wsp;
    wsp += (bytes + 255) & ~(size_t)255;
    return p;
  };
  short* xb     = (short*)alloc((size_t)2048 * 1024 * 2);
  short* btall  = (short*)alloc((size_t)4480 * 1024 * 2);
  short* owT    = (short*)alloc((size_t)1024 * 1024 * 2);
  short* fusedC = (short*)alloc((size_t)2048 * 4480 * 2);
  float* projf  = (float*)alloc((size_t)2048 * 384 * 4);
  float* biasA  = (float*)alloc((size_t)4480 * 4);
  short* vtg    = (short*)alloc((size_t)32 * 64 * 1024 * 2);
  short* attnO  = (short*)alloc((size_t)2048 * 1024 * 2);
  short* comb   = (short*)alloc((size_t)2048 * 1024 * 2);
  float* jwb    = (float*)alloc((size_t)32 * 6144 * 4);
  float* rlb    = (float*)alloc((size_t)32768 * 6 * 4);
  float* msb    = (float*)alloc((size_t)2048 * 16 * 4);
  float* Of     = (float*)alloc((size_t)1024 * 4096 * 4);
  float* Mlb    = (float*)alloc((size_t)1024 * 128 * 4);

  k_prep<<<8722, 256, 0, stream>>>(x, qkvw, mvw, ow, w1w, w2w, r1w, r2w, gw,
                                   qkvb, mvb, xb, btall, owT, biasA);

  k_gemmF<<<dim3(16, 35), 256, 0, stream>>>(xb, btall, fusedC, biasA, projf);

  k_vtr<<<dim3(32, 2, 32), dim3(32, 8), 0, stream>>>(fusedC, vtg);
  k_attn<<<1024, 256, 0, stream>>>(fusedC, vtg, Of, Mlb);
  k_amerge<<<2048, 256, 0, stream>>>(Of, Mlb, attnO);

  k_lines<<<128, 256, 0, stream>>>(projf, Jm, jwb, rlb);
  k_mscore<<<8192, 256, 0, stream>>>(jwb, rlb, dlog, msb);
  k_combine<<<2048, 256, 0, stream>>>(attnO, fusedC, projf, msb, msc, gb, comb);

  k_gemm<<<dim3(16, 8), 256, 0, stream>>>(comb, owT, out, ob, 1024, 1024);
}